// Round 2
// baseline (132.235 us; speedup 1.0000x reference)
//
#include <hip/hip_runtime.h>
#include <hip/hip_bf16.h>

#define NUM_BUCKETS 8192
#define ROW_THREADS 256
#define SCAN_THREADS 1024

typedef float f32x4 __attribute__((ext_vector_type(4)));

// Kernel 1: exclusive prefix sum of row_lengths -> offs[0..B], single block.
__global__ __launch_bounds__(SCAN_THREADS) void scan_rows_kernel(
    const int* __restrict__ row_len, int* __restrict__ offs, int B) {
    __shared__ int buf[SCAN_THREADS];
    __shared__ int carry_s;
    const int t = threadIdx.x;
    if (t == 0) carry_s = 0;
    __syncthreads();
    for (int base = 0; base < B; base += SCAN_THREADS) {
        const int i = base + t;
        const int v = (i < B) ? row_len[i] : 0;
        buf[t] = v;
        __syncthreads();
        // Hillis-Steele inclusive scan
        for (int off = 1; off < SCAN_THREADS; off <<= 1) {
            int add = (t >= off) ? buf[t - off] : 0;
            __syncthreads();
            buf[t] += add;
            __syncthreads();
        }
        const int carry = carry_s;
        __syncthreads();  // all reads of carry_s done before the update below
        if (i < B) offs[i] = carry + buf[t] - v;  // exclusive
        if (t == SCAN_THREADS - 1) {
            carry_s = carry + buf[t];
            if (base + SCAN_THREADS >= B) offs[B] = carry + buf[t];
        }
        __syncthreads();
    }
}

// Kernel 2: one block per row. Build the 8192-wide one-hot row in LDS,
// then stream it out with coalesced float4 nontemporal stores.
__global__ __launch_bounds__(ROW_THREADS) void nhot_row_kernel(
    const int* __restrict__ ids, const float* __restrict__ w,
    const int* __restrict__ offs, float* __restrict__ out) {
    __shared__ float lds[NUM_BUCKETS];
    const int r = blockIdx.x;
    const int t = threadIdx.x;

    #pragma unroll
    for (int k = 0; k < NUM_BUCKETS / ROW_THREADS; ++k)
        lds[k * ROW_THREADS + t] = 0.0f;
    __syncthreads();

    const int s = offs[r];
    const int e = offs[r + 1];
    for (int i = s + t; i < e; i += ROW_THREADS) {
        atomicAdd(&lds[ids[i]], w[i]);
    }
    __syncthreads();

    f32x4* outv = reinterpret_cast<f32x4*>(out + (size_t)r * NUM_BUCKETS);
    const f32x4* ldsv = reinterpret_cast<const f32x4*>(lds);
    #pragma unroll
    for (int k = 0; k < NUM_BUCKETS / 4 / ROW_THREADS; ++k) {  // 8 iters
        __builtin_nontemporal_store(ldsv[k * ROW_THREADS + t],
                                    &outv[k * ROW_THREADS + t]);
    }
}

extern "C" void kernel_launch(void* const* d_in, const int* in_sizes, int n_in,
                              void* d_out, int out_size, void* d_ws, size_t ws_size,
                              hipStream_t stream) {
    const int*   ids     = (const int*)d_in[0];    // values (NNZ,1) int32
    const int*   row_len = (const int*)d_in[1];    // row_lengths (B,1) int32
    const float* wvals   = (const float*)d_in[2];  // weight_values (NNZ,1) f32
    // d_in[3] = weight_row_lengths (unused by reference)

    const int B = in_sizes[1];
    float* out = (float*)d_out;
    int* offs = (int*)d_ws;  // needs (B+1)*4 bytes

    scan_rows_kernel<<<1, SCAN_THREADS, 0, stream>>>(row_len, offs, B);
    nhot_row_kernel<<<B, ROW_THREADS, 0, stream>>>(ids, wvals, offs, out);
}

// Round 3
// 118.261 us; speedup vs baseline: 1.1182x; 1.1182x over previous
//
#include <hip/hip_runtime.h>
#include <hip/hip_bf16.h>

#define NUM_BUCKETS 8192
#define ROW_THREADS 256

typedef float f32x4 __attribute__((ext_vector_type(4)));

// Kernel 1: exclusive prefix sum of row_lengths -> offs[0..B].
// Single block, 1024 threads, 16 elems/thread, shfl-based: ~4 barriers total
// per 16384-element chunk (vs ~320 in the Hillis-Steele version).
__global__ __launch_bounds__(1024) void scan_rows_kernel(
    const int* __restrict__ row_len, int* __restrict__ offs, int B) {
    __shared__ int wave_sums[16];
    __shared__ int carry_s;
    const int t = threadIdx.x;
    const int wave = t >> 6, lane = t & 63;
    if (t == 0) carry_s = 0;
    __syncthreads();
    const int CHUNK = 1024 * 16;
    for (int base = 0; base < B; base += CHUNK) {
        int v[16];
        const int idx0 = base + t * 16;
        int local = 0;
        #pragma unroll
        for (int e = 0; e < 16; ++e) {
            const int i = idx0 + e;
            const int x = (i < B) ? row_len[i] : 0;
            v[e] = local;          // exclusive within thread
            local += x;
        }
        // wave-level inclusive scan of per-thread sums (no barriers)
        int incl = local;
        #pragma unroll
        for (int d = 1; d < 64; d <<= 1) {
            const int y = __shfl_up(incl, d, 64);
            if (lane >= d) incl += y;
        }
        if (lane == 63) wave_sums[wave] = incl;
        __syncthreads();
        // wave 0 scans the 16 wave totals
        if (wave == 0) {
            int s = (lane < 16) ? wave_sums[lane] : 0;
            #pragma unroll
            for (int d = 1; d < 16; d <<= 1) {
                const int y = __shfl_up(s, d, 64);
                if (lane >= d) s += y;
            }
            if (lane < 16) wave_sums[lane] = s;  // inclusive wave sums
        }
        __syncthreads();
        const int carry = carry_s;
        const int wave_excl = (wave == 0) ? 0 : wave_sums[wave - 1];
        const int texcl = carry + wave_excl + (incl - local);
        #pragma unroll
        for (int e = 0; e < 16; ++e) {
            const int i = idx0 + e;
            if (i < B) offs[i] = texcl + v[e];
        }
        if (t == 0 && base + CHUNK >= B) offs[B] = carry + wave_sums[15];
        __syncthreads();
        if (t == 0) carry_s = carry + wave_sums[15];
        __syncthreads();
    }
}

// Kernel 2: one block per row. Build the 8192-wide one-hot row in LDS,
// then stream it out with coalesced 16B nontemporal stores.
__global__ __launch_bounds__(ROW_THREADS) void nhot_row_kernel(
    const int* __restrict__ ids, const float* __restrict__ w,
    const int* __restrict__ offs, float* __restrict__ out) {
    __shared__ float lds[NUM_BUCKETS];
    const int r = blockIdx.x;
    const int t = threadIdx.x;

    // vectorized zero: 8 x ds_write_b128 per thread
    f32x4* ldsv = reinterpret_cast<f32x4*>(lds);
    const f32x4 z = {0.f, 0.f, 0.f, 0.f};
    #pragma unroll
    for (int k = 0; k < NUM_BUCKETS / 4 / ROW_THREADS; ++k)
        ldsv[k * ROW_THREADS + t] = z;
    __syncthreads();

    const int s = offs[r];
    const int e = offs[r + 1];
    for (int i = s + t; i < e; i += ROW_THREADS) {
        atomicAdd(&lds[ids[i]], w[i]);
    }
    __syncthreads();

    f32x4* outv = reinterpret_cast<f32x4*>(out + (size_t)r * NUM_BUCKETS);
    #pragma unroll
    for (int k = 0; k < NUM_BUCKETS / 4 / ROW_THREADS; ++k) {  // 8 iters
        __builtin_nontemporal_store(ldsv[k * ROW_THREADS + t],
                                    &outv[k * ROW_THREADS + t]);
    }
}

extern "C" void kernel_launch(void* const* d_in, const int* in_sizes, int n_in,
                              void* d_out, int out_size, void* d_ws, size_t ws_size,
                              hipStream_t stream) {
    const int*   ids     = (const int*)d_in[0];    // values (NNZ,1) int32
    const int*   row_len = (const int*)d_in[1];    // row_lengths (B,1) int32
    const float* wvals   = (const float*)d_in[2];  // weight_values (NNZ,1) f32
    // d_in[3] = weight_row_lengths (unused by reference)

    const int B = in_sizes[1];
    float* out = (float*)d_out;
    int* offs = (int*)d_ws;  // needs (B+1)*4 bytes

    scan_rows_kernel<<<1, 1024, 0, stream>>>(row_len, offs, B);
    nhot_row_kernel<<<B, ROW_THREADS, 0, stream>>>(ids, wvals, offs, out);
}